// Round 1
// 503.955 us; speedup vs baseline: 1.0088x; 1.0088x over previous
//
#include <hip/hip_runtime.h>

#define H  400
#define NB 16
#define CI 4
#define CO 32

// ---------------- K1: transpose each 400x400 plane of X into XT ----------------
// 80x80 tiles, float4 global loads AND stores. 64 nc-planes * 25 tiles = 1600 blocks.
#define TT 80
__global__ __launch_bounds__(256) void k_transpose(const float* __restrict__ x,
                                                   float* __restrict__ xt) {
    __shared__ float tile[TT][TT + 5];   // pad 85: store-phase stride 4*85%32=21 (coprime w/ 32)
    int b = blockIdx.x;
    int tj = b % 5;
    int ti = (b / 5) % 5;
    int nc = b / 25;
    const float* src = x + (size_t)nc * H * H;
    float* dst = xt + (size_t)nc * H * H;
    int i0 = ti * TT, j0 = tj * TT;
    for (int e = threadIdx.x; e < TT * 20; e += 256) {
        int r = e / 20, q = e % 20;
        float4 v = ((const float4*)(src + (size_t)(i0 + r) * H + j0))[q];
        tile[r][q * 4 + 0] = v.x; tile[r][q * 4 + 1] = v.y;
        tile[r][q * 4 + 2] = v.z; tile[r][q * 4 + 3] = v.w;
    }
    __syncthreads();
    for (int e = threadIdx.x; e < TT * 20; e += 256) {
        int r = e / 20, q = e % 20;
        float4 v;
        v.x = tile[q * 4 + 0][r]; v.y = tile[q * 4 + 1][r];
        v.z = tile[q * 4 + 2][r]; v.w = tile[q * 4 + 3][r];
        ((float4*)(dst + (size_t)(j0 + r) * H + i0))[q] = v;
    }
}

// ---------------- K2: partial rows/cols, k-split x5 ----------------
// rowsP[ks][m][n*32+o] layout: per-block stores are 64-consecutive-dword bursts
// (slot == tid), eliminating the 4B/1600B-stride scatter that caused per-sector
// RMW traffic across XCD L2s.
#define KC 40
#define KSPLIT 5
__global__ __launch_bounds__(256) void k_rowscols(const float* __restrict__ x,
        const float* __restrict__ xt, const float* __restrict__ L,
        float* __restrict__ rowsP, float* __restrict__ colsP)
{
    __shared__ __align__(16) float4 Lm[CO * CI];      // L[o,c,m,:]
    __shared__ __align__(16) float Xr[NB * CI * KC];
    __shared__ __align__(16) float Xc[NB * CI * KC];
    __shared__ __align__(16) float Tr[CO * 164];      // o*164 + c*KC + k
    int b = blockIdx.x;
    int m  = b / KSPLIT;
    int ks = b % KSPLIT;
    int tid = threadIdx.x;
    const float4* L4 = (const float4*)L;
    if (tid < CO * CI) Lm[tid] = L4[tid * H + m];

    int o  = tid & 31;
    int n0 = tid >> 5;     // 0..7
    float ar0 = 0.f, ar1 = 0.f, ac0 = 0.f, ac1 = 0.f;

    for (int ch = 0; ch < 2; ++ch) {
        int k0 = ks * 80 + ch * KC;
        __syncthreads();
        for (int e = tid; e < NB * CI * KC / 4; e += 256) {   // 640 float4s
            int q  = e % 10;
            int nc = e / 10;
            ((float4*)Xr)[e] = *(const float4*)(x  + (size_t)(nc * H + m) * H + k0 + q * 4);
            ((float4*)Xc)[e] = *(const float4*)(xt + (size_t)(nc * H + m) * H + k0 + q * 4);
        }
        for (int e = tid; e < CO * CI * KC; e += 256) {       // 5120
            int k  = e % KC;
            int oc = e / KC;
            float4 lv = L4[oc * H + k0 + k];
            float4 lm = Lm[oc];
            Tr[(oc >> 2) * 164 + (oc & 3) * KC + k] =
                lv.x * lm.x + lv.y * lm.y + lv.z * lm.z + lv.w * lm.w;
        }
        __syncthreads();
        #pragma unroll
        for (int c = 0; c < CI; ++c) {
            const float4* trp = (const float4*)(Tr + o * 164 + c * KC);
            const float4* pr0 = (const float4*)(Xr + (n0 * CI + c) * KC);
            const float4* pr1 = (const float4*)(Xr + ((n0 + 8) * CI + c) * KC);
            const float4* pc0 = (const float4*)(Xc + (n0 * CI + c) * KC);
            const float4* pc1 = (const float4*)(Xc + ((n0 + 8) * CI + c) * KC);
            #pragma unroll
            for (int q = 0; q < KC / 4; ++q) {
                float4 tv = trp[q];
                float4 a  = pr0[q];
                float4 bb = pr1[q];
                float4 cc = pc0[q];
                float4 dd = pc1[q];
                ar0 += tv.x * a.x  + tv.y * a.y  + tv.z * a.z  + tv.w * a.w;
                ar1 += tv.x * bb.x + tv.y * bb.y + tv.z * bb.z + tv.w * bb.w;
                ac0 += tv.x * cc.x + tv.y * cc.y + tv.z * cc.z + tv.w * cc.w;
                ac1 += tv.x * dd.x + tv.y * dd.y + tv.z * dd.z + tv.w * dd.w;
            }
        }
    }
    // slot = n*CO + o: for ar0 slot == tid, for ar1 slot == tid + 256.
    size_t base = ((size_t)ks * H + m) * (NB * CO);
    rowsP[base + tid]       = ar0;
    rowsP[base + 256 + tid] = ar1;
    colsP[base + tid]       = ac0;
    colsP[base + 256 + tid] = ac1;
}

// ---------------- K2b: reduce the 5 partials + transpose to [n][o][m] ----------------
// Writes coalesced (m fastest); reads are 2KB-strided but L2-hot (lines reused across no).
__global__ __launch_bounds__(256) void k_reduce(const float* __restrict__ rowsP,
        const float* __restrict__ colsP, float* __restrict__ rows, float* __restrict__ cols)
{
    int i = blockIdx.x * 256 + threadIdx.x;    // NB*CO*H = 204800 total, grid exact
    int m  = i % H;
    int no = i / H;
    float s = 0.f, t = 0.f;
    #pragma unroll
    for (int k = 0; k < KSPLIT; ++k) {
        s += rowsP[((size_t)k * H + m) * (NB * CO) + no];
        t += colsP[((size_t)k * H + m) * (NB * CO) + no];
    }
    rows[(size_t)no * H + m] = s;
    cols[(size_t)no * H + m] = t;
}

// ---------------- K3: final output ----------------
// 16x16 spatial tile, 256 threads (4 waves, o = wave id), X staged in two 8-n halves.
// LDS 36 KB -> 4 blocks/CU -> 1024-block capacity >= 625 grid -> single dispatch round
// (old version: 80 KB -> 2/CU -> 512 capacity -> 113-block tail round at 22% occupancy).
#define TS 16
__global__ __launch_bounds__(256, 4) void k_out(const float* __restrict__ x,
        const float* __restrict__ L, const float* __restrict__ bias,
        const float* __restrict__ rows, const float* __restrict__ cols,
        float* __restrict__ out)
{
    __shared__ __align__(16) float Xl[8 * CI * TS * TS];   // 32 KB [n'][c][ii][jj]
    __shared__ __align__(16) float rT[8 * 4 * TS];         // 2 KB  [n'][oo][ii]
    __shared__ __align__(16) float cT[8 * 4 * TS];         // 2 KB  [n'][oo][jj]
    int b = blockIdx.x;
    int ti = b / 25, tj = b % 25;
    int i0 = ti * TS, j0 = tj * TS;
    int tid = threadIdx.x;

    int o  = tid >> 6;             // 0..3 (wave id)
    int u  = tid & 63;
    int ii = u >> 2, jq = u & 3;
    const float4* x4  = (const float4*)x;
    const float4* L4  = (const float4*)L;
    const float4* cT4 = (const float4*)cT;
    float4* Xl4  = (float4*)Xl;
    float4* out4 = (float4*)out;

    for (int nh = 0; nh < 2; ++nh) {
        if (nh) __syncthreads();           // all nh=0 readers done before Xl overwrite
        for (int e = tid; e < 8 * CI * TS * 4; e += 256) {   // 2048 float4 = 32 KB
            int q   = e & 3;
            int iiw = (e >> 2) & 15;
            int nc  = nh * (8 * CI) + (e >> 6);   // global n*CI+c
            Xl4[e] = x4[(size_t)(nc * H + i0 + iiw) * 100 + tj * 4 + q];
        }
        for (int os = 0; os < 8; ++os) {
            int og = os * 4 + o;
            float4 T4[CI];
            #pragma unroll
            for (int c = 0; c < CI; ++c) {
                float4 Li = L4[(og * CI + c) * H + i0 + ii];
                float4 La = L4[(og * CI + c) * H + j0 + jq * 4 + 0];
                float4 Lb = L4[(og * CI + c) * H + j0 + jq * 4 + 1];
                float4 Lc = L4[(og * CI + c) * H + j0 + jq * 4 + 2];
                float4 Ld = L4[(og * CI + c) * H + j0 + jq * 4 + 3];
                T4[c].x = Li.x * La.x + Li.y * La.y + Li.z * La.z + Li.w * La.w;
                T4[c].y = Li.x * Lb.x + Li.y * Lb.y + Li.z * Lb.z + Li.w * Lb.w;
                T4[c].z = Li.x * Lc.x + Li.y * Lc.y + Li.z * Lc.z + Li.w * Lc.w;
                T4[c].w = Li.x * Ld.x + Li.y * Ld.y + Li.z * Ld.z + Li.w * Ld.w;
            }
            float bo = bias[og];

            __syncthreads();   // covers Xl staging (os==0) and prev rT/cT readers
            for (int e = tid; e < 8 * 4 * TS; e += 256) {    // 512 elements
                int iw = e & 15;
                int oo = (e >> 4) & 3;
                int np = e >> 6;                  // 0..7
                int n  = nh * 8 + np;
                rT[e] = rows[(size_t)(n * CO + os * 4 + oo) * H + i0 + iw];
                cT[e] = cols[(size_t)(n * CO + os * 4 + oo) * H + j0 + iw];
            }
            __syncthreads();

            for (int np = 0; np < 8; ++np) {
                float ra  = rT[(np * 4 + o) * TS + ii] + bo;
                float4 ca = cT4[(np * 4 + o) * 4 + jq];
                float4 acc;
                acc.x = ra + ca.x; acc.y = ra + ca.y; acc.z = ra + ca.z; acc.w = ra + ca.w;
                #pragma unroll
                for (int c = 0; c < CI; ++c) {
                    float4 xv = Xl4[((np * CI + c) * TS + ii) * 4 + jq];
                    acc.x -= xv.x * T4[c].x;
                    acc.y -= xv.y * T4[c].y;
                    acc.z -= xv.z * T4[c].z;
                    acc.w -= xv.w * T4[c].w;
                }
                int n = nh * 8 + np;
                out4[((size_t)(n * CO + og) * H + i0 + ii) * 100 + tj * 4 + jq] = acc;
            }
        }
    }
}

extern "C" void kernel_launch(void* const* d_in, const int* in_sizes, int n_in,
                              void* d_out, int out_size, void* d_ws, size_t ws_size,
                              hipStream_t stream) {
    const float* x    = (const float*)d_in[0];
    const float* L    = (const float*)d_in[1];
    const float* bias = (const float*)d_in[2];
    float* out = (float*)d_out;
    char* ws = (char*)d_ws;

    size_t xt_bytes = (size_t)NB * CI * H * H * sizeof(float);       // 40,960,000
    size_t rc_elems = (size_t)NB * CO * H;                           // 204,800
    size_t rcP_bytes = (size_t)KSPLIT * rc_elems * sizeof(float);    // 4,096,000
    size_t rc_bytes  = rc_elems * sizeof(float);

    float* XT    = (float*)ws;
    float* rowsP = (float*)(ws + xt_bytes);
    float* colsP = (float*)(ws + xt_bytes + rcP_bytes);
    float* rows  = (float*)(ws + xt_bytes + 2 * rcP_bytes);
    float* cols  = (float*)(ws + xt_bytes + 2 * rcP_bytes + rc_bytes);
    (void)ws_size;

    k_transpose<<<1600, 256, 0, stream>>>(x, XT);
    k_rowscols<<<H * KSPLIT, 256, 0, stream>>>(x, XT, L, rowsP, colsP);
    k_reduce<<<(NB * CO * H) / 256, 256, 0, stream>>>(rowsP, colsP, rows, cols);
    k_out<<<625, 256, 0, stream>>>(x, L, bias, rows, cols, out);
}